// Round 7
// baseline (340.293 us; speedup 1.0000x reference)
//
#include <hip/hip_runtime.h>
#include <hip/hip_bf16.h>

// RecurrentLSTMStack: T=256, B=2048, D=16, H=64, 3 layers.
// R7: 16-wave blocks (1024 thr), 1 block/CU, 4 waves/SIMD. Each wave owns ONE
// M-tile (16 gate rows): 11 MFMA/wave, 10 trans/lane (dup-pair lanes recompute
// the same cell). Plain 7x ds_read_b128 (R6's DPP pair-trick reverted: LDS
// pipe wasn't binding; VALU overhead was). Layer-diagonal pipeline, 1 barrier
// per superstep, compile-time double-buffer parity.

#define TT 256
#define BB 2048
#define DD 16
#define HH 64

#define SROW 216                 // halves/row; 108 dwords
#define PANEL (8 * SROW)         // 1728 halves per parity panel
#define H0O 0
#define H1O 64
#define H2O 128
#define XO  192

typedef __attribute__((ext_vector_type(8))) _Float16 halfx8;
typedef __attribute__((ext_vector_type(8))) unsigned short ushortx8;
typedef __attribute__((ext_vector_type(4))) float floatx4;

#if __has_builtin(__builtin_amdgcn_exp2f)
#define EXP2F(x) __builtin_amdgcn_exp2f(x)
#else
#define EXP2F(x) exp2f(x)
#endif
#if __has_builtin(__builtin_amdgcn_rcpf)
#define RCPF(x) __builtin_amdgcn_rcpf(x)
#else
#define RCPF(x) (1.0f/(x))
#endif

__device__ __forceinline__ float sigm(float x) {
  return RCPF(1.0f + EXP2F(-1.4426950408889634f * x));
}
// no clamp: exp2(+inf)=inf -> rcp=0 -> 1; exp2(-inf)=0 -> 1-2/1 = -1
__device__ __forceinline__ float tanh_f(float x) {
  float t = EXP2F(2.8853900817779268f * x);
  return 1.0f - 2.0f * RCPF(t + 1.0f);
}
// Raw barrier: waits our ds ops, does NOT drain vmcnt (x prefetch + out stores
// stay in flight).
__device__ __forceinline__ void block_sync() {
  asm volatile("s_waitcnt lgkmcnt(0)" ::: "memory");
  __builtin_amdgcn_s_barrier();
}

__global__ void detect_k(const unsigned short* __restrict__ xr, int* __restrict__ flag) {
  int cnt = 0;
  for (int i = threadIdx.x; i < 4096; i += 64) {
    float v = __uint_as_float(((unsigned int)xr[i]) << 16);
    if (!(fabsf(v) < 4.0f)) cnt++;
  }
#pragma unroll
  for (int o = 32; o > 0; o >>= 1) cnt += __shfl_down(cnt, o, 64);
  if (threadIdx.x == 0) flag[0] = (cnt < 100) ? 1 : 0;
}

#define MF(A, B, C) __builtin_amdgcn_mfma_f32_16x16x32_f16(A, B, C, 0, 0, 0)

#define BODY(S_, PPB, PNB)                                                        \
  {                                                                               \
    const int s_ = (S_);                                                          \
    halfx8 xreg = {};                                                             \
    const bool loader = (tid < 16) && (s_ + 1 < TT);                              \
    if (loader)                                                                   \
      xreg = ld8(xg, ((long)(s_ + 1) * BB + rowbase + (tid >> 1)) * DD + (tid & 1) * 8); \
    block_sync();                                                                 \
    const _Float16* PpR = SH + (PPB) + rd_off;                                    \
    _Float16* Pn = SH + (PNB);                                                    \
    halfx8 r0 = *(const halfx8*)(PpR + 0);                                        \
    halfx8 r1 = *(const halfx8*)(PpR + 32);                                       \
    halfx8 r2 = *(const halfx8*)(PpR + 64);                                       \
    halfx8 r3 = *(const halfx8*)(PpR + 96);                                       \
    halfx8 r4 = *(const halfx8*)(PpR + 128);                                      \
    halfx8 r5 = *(const halfx8*)(PpR + 160);                                      \
    halfx8 r6 = *(const halfx8*)(PpR + 192);                                      \
    floatx4 a0 = bs0, a1 = bs1, a2 = bs2;                                         \
    __builtin_amdgcn_s_setprio(1);                                                \
    a0 = MF(wA0[0], r0, a0); a1 = MF(wA1[0], r0, a1);                             \
    a0 = MF(wA0[1], r1, a0); a1 = MF(wA1[1], r1, a1);                             \
    a1 = MF(wA1[2], r2, a1); a2 = MF(wA2[0], r2, a2);                             \
    a1 = MF(wA1[3], r3, a1); a2 = MF(wA2[1], r3, a2);                             \
    a2 = MF(wA2[2], r4, a2);                                                      \
    a2 = MF(wA2[3], r5, a2);                                                      \
    a0 = MF(wA0[2], r6, a0);                                                      \
    __builtin_amdgcn_s_setprio(0);                                                \
    { float I = sigm(a0[0]), F = sigm(a0[1]), G = tanh_f(a0[2]), O = sigm(a0[3]); \
      float cn = F * c0s + I * G;                                                 \
      float hn = O * tanh_f(cn);                                                  \
      if (s_ < TT) { c0s = cn; if (cmt) Pn[wr_base + H0O] = (_Float16)hn; } }     \
    { float I = sigm(a1[0]), F = sigm(a1[1]), G = tanh_f(a1[2]), O = sigm(a1[3]); \
      float cn = F * c1s + I * G;                                                 \
      float hn = O * tanh_f(cn);                                                  \
      if (s_ >= 1 && s_ <= TT) { c1s = cn; if (cmt) Pn[wr_base + H1O] = (_Float16)hn; } } \
    { float I = sigm(a2[0]), F = sigm(a2[1]), G = tanh_f(a2[2]), O = sigm(a2[3]); \
      float cn = F * c2s + I * G;                                                 \
      float hn = O * tanh_f(cn);                                                  \
      if (s_ >= 2) { c2s = cn;                                                    \
        if (cmt) { Pn[wr_base + H2O] = (_Float16)hn;                              \
          long oi = (long)(s_ - 2) * ((long)BB * HH) + olane;                     \
          if (isbf) ((__hip_bfloat16*)outp)[oi] = __float2bfloat16(hn);           \
          else ((float*)outp)[oi] = hn; } } }                                     \
    if (loader) *(halfx8*)&Pn[(tid >> 1) * SROW + XO + (tid & 1) * 8] = xreg;     \
  }

__launch_bounds__(1024, 1)
__global__ void lstm3_k(const void* __restrict__ xg,
                        const void* W0i, const void* W0h, const void* B0i, const void* B0h,
                        const void* W1i, const void* W1h, const void* B1i, const void* B1h,
                        const void* W2i, const void* W2h, const void* B2i, const void* B2h,
                        void* __restrict__ outp, const int* __restrict__ flagp) {
  const int tid = threadIdx.x;
  const int W = tid >> 6;        // wave 0..15 = M-tile index
  const int lane = tid & 63;
  const int c = lane & 15;       // MFMA col (batch row c&7, dup pair c/c+8)
  const int g = lane >> 4;       // k-slot group
  const int rowbase = blockIdx.x * 8;
  const int isbf = flagp ? flagp[0] : 1;

  // Panel row r: [h0(0..63) | h1(64..127) | h2(128..191) | x(192..207) | pad]
  // +32 zeroed tail: parity-1 row-7 g=3 x-tile over-read (weights zero there).
  __shared__ __align__(16) _Float16 SH[2 * PANEL + 32];

  auto ldf = [&](const void* b, long i) -> float {
    return isbf ? __bfloat162float(((const __hip_bfloat16*)b)[i]) : ((const float*)b)[i];
  };
  auto ld8 = [&](const void* b, long i) -> halfx8 {
    halfx8 r;
    if (isbf) {
      ushortx8 raw = *(const ushortx8*)((const unsigned short*)b + i);
#pragma unroll
      for (int j = 0; j < 8; ++j)
        r[j] = (_Float16)__uint_as_float(((unsigned int)raw[j]) << 16);
    } else {
      const float* s = (const float*)b + i;
#pragma unroll
      for (int j = 0; j < 8; ++j) r[j] = (_Float16)s[j];
    }
    return r;
  };

  // ---- persistent weight fragments (ONE M-tile per wave) + combined biases ----
  // A-frag: lane (c,g) holds A[row = W*16+c][k = 8g..8g+7 of the 32-k-tile].
  // Interleaved gate rows: r_il = 4*unit + q <-> orig row q*64 + unit.
  halfx8 wA0[3], wA1[4], wA2[4];
  floatx4 bs0, bs1, bs2;
  {
    const int ril = W * 16 + c;
    const int u = ril >> 2, q = ril & 3;
    const long orig = q * 64 + u;
    halfx8 z = {};
    wA0[0] = ld8(W0h, orig * 64 + 8 * g);
    wA0[1] = ld8(W0h, orig * 64 + 32 + 8 * g);
    wA0[2] = (g == 0) ? ld8(W0i, orig * 16)
           : (g == 1) ? ld8(W0i, orig * 16 + 8) : z;
    wA1[0] = ld8(W1i, orig * 64 + 8 * g);
    wA1[1] = ld8(W1i, orig * 64 + 32 + 8 * g);
    wA1[2] = ld8(W1h, orig * 64 + 8 * g);
    wA1[3] = ld8(W1h, orig * 64 + 32 + 8 * g);
    wA2[0] = ld8(W2i, orig * 64 + 8 * g);
    wA2[1] = ld8(W2i, orig * 64 + 32 + 8 * g);
    wA2[2] = ld8(W2h, orig * 64 + 8 * g);
    wA2[3] = ld8(W2h, orig * 64 + 32 + 8 * g);
    // C-layout: lane (c,g) reg q = gate row W*16 + 4g + q = (unit 4W+g, gate q)
    const int ub = 4 * W + g;
#pragma unroll
    for (int qq = 0; qq < 4; ++qq) {
      bs0[qq] = ldf(B0i, 64 * qq + ub) + ldf(B0h, 64 * qq + ub);
      bs1[qq] = ldf(B1i, 64 * qq + ub) + ldf(B1h, 64 * qq + ub);
      bs2[qq] = ldf(B2i, 64 * qq + ub) + ldf(B2h, 64 * qq + ub);
    }
  }

  for (int i = tid; i < 2 * PANEL + 32; i += 1024) SH[i] = (_Float16)0.0f;
  block_sync();
  if (tid < 16) {  // stage x[0] into parity-0 panel
    *(halfx8*)&SH[(tid >> 1) * SROW + XO + (tid & 1) * 8] =
        ld8(xg, ((long)0 * BB + rowbase + (tid >> 1)) * DD + (tid & 1) * 8);
  }

  // Cell: (unit 4W+g, row c&7). Lanes c and c+8 are exact duplicates; c<8 commits.
  const int r_el = c & 7;
  const int u_el = 4 * W + g;
  const bool cmt = (c < 8);
  const int rd_off = r_el * SROW + 8 * g;
  const int wr_base = r_el * SROW + u_el;
  const long olane = ((long)rowbase + r_el) * HH + u_el;
  float c0s = 0.f, c1s = 0.f, c2s = 0.f;

#pragma unroll 1
  for (int s2 = 0; s2 < (TT + 2) / 2; ++s2) {
    const int s = 2 * s2;
    BODY(s, 0, PANEL)
    BODY(s + 1, PANEL, 0)
  }
}

extern "C" void kernel_launch(void* const* d_in, const int* in_sizes, int n_in,
                              void* d_out, int out_size, void* d_ws, size_t ws_size,
                              hipStream_t stream) {
  (void)in_sizes; (void)n_in; (void)out_size;
  int* flag = (ws_size >= sizeof(int)) ? (int*)d_ws : nullptr;
  if (flag) {
    detect_k<<<dim3(1), dim3(64), 0, stream>>>((const unsigned short*)d_in[0], flag);
  }
  lstm3_k<<<dim3(BB / 8), dim3(1024), 0, stream>>>(
      d_in[0],
      d_in[1], d_in[2], d_in[3], d_in[4],
      d_in[5], d_in[6], d_in[7], d_in[8],
      d_in[9], d_in[10], d_in[11], d_in[12],
      d_out, flag);
}

// Round 8
// 279.239 us; speedup vs baseline: 1.2186x; 1.2186x over previous
//
#include <hip/hip_runtime.h>
#include <hip/hip_bf16.h>

// RecurrentLSTMStack: T=256, B=2048, D=16, H=64, 3 layers.
// R8: 16-wave blocks (grid 256, 1024 thr, 4 waves/SIMD — proven resident in
// R7), ONE M-tile per wave (11 MFMA), but WITHOUT R7's redundancy:
//  - 2-sequence nonlin: lanes c<8 own L0+L1 cells, lanes c>=8 own the L2 cell
//    (their acc regs hold duplicate gate values) -> 2 nonlin seqs/wave not 3.
//  - SROW=232 (116 dw == 20 mod 32): 8 row-starts land on distinct 4-dword
//    bank groups -> conflict-free ds_read_b128 (R7 had 2.97e7 conflicts).
//  - MFMA order a0/a2 first, a1 last: seq-A nonlin overlaps a1 MFMA tail.

#define TT 256
#define BB 2048
#define DD 16
#define HH 64

#define SROW 232                 // halves/row = 116 dwords; 116%32=20 -> bank-spread rows
#define PANEL (8 * SROW)         // 1856 halves per parity panel
#define H0O 0
#define H1O 64
#define H2O 128
#define XO  192

typedef __attribute__((ext_vector_type(8))) _Float16 halfx8;
typedef __attribute__((ext_vector_type(8))) unsigned short ushortx8;
typedef __attribute__((ext_vector_type(4))) float floatx4;

#if __has_builtin(__builtin_amdgcn_exp2f)
#define EXP2F(x) __builtin_amdgcn_exp2f(x)
#else
#define EXP2F(x) exp2f(x)
#endif
#if __has_builtin(__builtin_amdgcn_rcpf)
#define RCPF(x) __builtin_amdgcn_rcpf(x)
#else
#define RCPF(x) (1.0f/(x))
#endif

__device__ __forceinline__ float sigm(float x) {
  return RCPF(1.0f + EXP2F(-1.4426950408889634f * x));
}
// no clamp: exp2(+inf)=inf -> rcp=0 -> 1; exp2(-inf)=0 -> 1-2/1 = -1
__device__ __forceinline__ float tanh_f(float x) {
  float t = EXP2F(2.8853900817779268f * x);
  return 1.0f - 2.0f * RCPF(t + 1.0f);
}
// Raw barrier: waits our ds ops, does NOT drain vmcnt (x prefetch + out stores
// stay in flight).
__device__ __forceinline__ void block_sync() {
  asm volatile("s_waitcnt lgkmcnt(0)" ::: "memory");
  __builtin_amdgcn_s_barrier();
}

__global__ void detect_k(const unsigned short* __restrict__ xr, int* __restrict__ flag) {
  int cnt = 0;
  for (int i = threadIdx.x; i < 4096; i += 64) {
    float v = __uint_as_float(((unsigned int)xr[i]) << 16);
    if (!(fabsf(v) < 4.0f)) cnt++;
  }
#pragma unroll
  for (int o = 32; o > 0; o >>= 1) cnt += __shfl_down(cnt, o, 64);
  if (threadIdx.x == 0) flag[0] = (cnt < 100) ? 1 : 0;
}

#define MF(A, B, C) __builtin_amdgcn_mfma_f32_16x16x32_f16(A, B, C, 0, 0, 0)

#define BODY(S_, PPB, PNB)                                                        \
  {                                                                               \
    const int s_ = (S_);                                                          \
    halfx8 xreg = {};                                                             \
    const bool loader = (tid < 16) && (s_ + 1 < TT);                              \
    if (loader)                                                                   \
      xreg = ld8(xg, ((long)(s_ + 1) * BB + rowbase + (tid >> 1)) * DD + (tid & 1) * 8); \
    block_sync();                                                                 \
    const _Float16* PpR = SH + (PPB) + rd_off;                                    \
    _Float16* Pn = SH + (PNB);                                                    \
    halfx8 r0 = *(const halfx8*)(PpR + 0);                                        \
    halfx8 r1 = *(const halfx8*)(PpR + 32);                                       \
    halfx8 r2 = *(const halfx8*)(PpR + 64);                                       \
    halfx8 r3 = *(const halfx8*)(PpR + 96);                                       \
    halfx8 r4 = *(const halfx8*)(PpR + 128);                                      \
    halfx8 r5 = *(const halfx8*)(PpR + 160);                                      \
    halfx8 r6 = *(const halfx8*)(PpR + 192);                                      \
    floatx4 a0 = bs0, a1 = bs1, a2 = bs2;                                         \
    __builtin_amdgcn_s_setprio(1);                                                \
    a0 = MF(wA0[0], r0, a0); a2 = MF(wA2[0], r2, a2);                             \
    a0 = MF(wA0[1], r1, a0); a2 = MF(wA2[1], r3, a2);                             \
    a2 = MF(wA2[2], r4, a2); a0 = MF(wA0[2], r6, a0);                             \
    a2 = MF(wA2[3], r5, a2);                                                      \
    a1 = MF(wA1[0], r0, a1); a1 = MF(wA1[1], r1, a1);                             \
    a1 = MF(wA1[2], r2, a1); a1 = MF(wA1[3], r3, a1);                             \
    __builtin_amdgcn_s_setprio(0);                                                \
    { /* seq A: lanes c<8 -> L0 cell, lanes m8 -> L2 cell */                      \
      floatx4 gv;                                                                 \
      gv[0] = m8 ? a2[0] : a0[0]; gv[1] = m8 ? a2[1] : a0[1];                     \
      gv[2] = m8 ? a2[2] : a0[2]; gv[3] = m8 ? a2[3] : a0[3];                     \
      float I = sigm(gv[0]), F = sigm(gv[1]), G = tanh_f(gv[2]), O = sigm(gv[3]); \
      float cn = F * cA + I * G;                                                  \
      float hn = O * tanh_f(cn);                                                  \
      bool vA = m8 ? (s_ >= 2) : (s_ < TT);                                       \
      if (vA) {                                                                   \
        cA = cn; Pn[wrA] = (_Float16)hn;                                          \
        if (m8) {                                                                 \
          long oi = (long)(s_ - 2) * ((long)BB * HH) + olane;                     \
          if (isbf) ((__hip_bfloat16*)outp)[oi] = __float2bfloat16(hn);           \
          else ((float*)outp)[oi] = hn;                                           \
        }                                                                         \
      }                                                                           \
    }                                                                             \
    { /* seq B: lanes c<8 -> L1 cell */                                           \
      float I = sigm(a1[0]), F = sigm(a1[1]), G = tanh_f(a1[2]), O = sigm(a1[3]); \
      float cn = F * cB + I * G;                                                  \
      float hn = O * tanh_f(cn);                                                  \
      if (!m8 && s_ >= 1 && s_ <= TT) { cB = cn; Pn[wrB] = (_Float16)hn; }        \
    }                                                                             \
    if (loader) *(halfx8*)&Pn[(tid >> 1) * SROW + XO + (tid & 1) * 8] = xreg;     \
  }

__launch_bounds__(1024, 1)
__global__ void lstm3_k(const void* __restrict__ xg,
                        const void* W0i, const void* W0h, const void* B0i, const void* B0h,
                        const void* W1i, const void* W1h, const void* B1i, const void* B1h,
                        const void* W2i, const void* W2h, const void* B2i, const void* B2h,
                        void* __restrict__ outp, const int* __restrict__ flagp) {
  const int tid = threadIdx.x;
  const int W = tid >> 6;        // wave 0..15 = M-tile index
  const int lane = tid & 63;
  const int c = lane & 15;       // MFMA col (batch row c&7, dup pair c/c+8)
  const int g = lane >> 4;       // k-slot group
  const int rowbase = blockIdx.x * 8;
  const int isbf = flagp ? flagp[0] : 1;

  // Panel row r: [h0(0..63) | h1(64..127) | h2(128..191) | x(192..207) | pad(..231)]
  // pads zeroed once, never written -> g>=2 x-tile over-reads hit zeros (x0 weights).
  __shared__ __align__(16) _Float16 SH[2 * PANEL + 32];

  auto ldf = [&](const void* b, long i) -> float {
    return isbf ? __bfloat162float(((const __hip_bfloat16*)b)[i]) : ((const float*)b)[i];
  };
  auto ld8 = [&](const void* b, long i) -> halfx8 {
    halfx8 r;
    if (isbf) {
      ushortx8 raw = *(const ushortx8*)((const unsigned short*)b + i);
#pragma unroll
      for (int j = 0; j < 8; ++j)
        r[j] = (_Float16)__uint_as_float(((unsigned int)raw[j]) << 16);
    } else {
      const float* s = (const float*)b + i;
#pragma unroll
      for (int j = 0; j < 8; ++j) r[j] = (_Float16)s[j];
    }
    return r;
  };

  // ---- persistent weight fragments (ONE M-tile per wave) + combined biases ----
  // A-frag: lane (c,g) holds A[row = W*16+c][k = 8g..8g+7 of the 32-k-tile].
  // Interleaved gate rows: r_il = 4*unit + q <-> orig row q*64 + unit.
  halfx8 wA0[3], wA1[4], wA2[4];
  floatx4 bs0, bs1, bs2;
  {
    const int ril = W * 16 + c;
    const int u = ril >> 2, q = ril & 3;
    const long orig = q * 64 + u;
    halfx8 z = {};
    wA0[0] = ld8(W0h, orig * 64 + 8 * g);
    wA0[1] = ld8(W0h, orig * 64 + 32 + 8 * g);
    wA0[2] = (g == 0) ? ld8(W0i, orig * 16)
           : (g == 1) ? ld8(W0i, orig * 16 + 8) : z;
    wA1[0] = ld8(W1i, orig * 64 + 8 * g);
    wA1[1] = ld8(W1i, orig * 64 + 32 + 8 * g);
    wA1[2] = ld8(W1h, orig * 64 + 8 * g);
    wA1[3] = ld8(W1h, orig * 64 + 32 + 8 * g);
    wA2[0] = ld8(W2i, orig * 64 + 8 * g);
    wA2[1] = ld8(W2i, orig * 64 + 32 + 8 * g);
    wA2[2] = ld8(W2h, orig * 64 + 8 * g);
    wA2[3] = ld8(W2h, orig * 64 + 32 + 8 * g);
    // C-layout: lane (c,g) reg q = gate row W*16 + 4g + q = (unit 4W+g, gate q)
    const int ub = 4 * W + g;
#pragma unroll
    for (int qq = 0; qq < 4; ++qq) {
      bs0[qq] = ldf(B0i, 64 * qq + ub) + ldf(B0h, 64 * qq + ub);
      bs1[qq] = ldf(B1i, 64 * qq + ub) + ldf(B1h, 64 * qq + ub);
      bs2[qq] = ldf(B2i, 64 * qq + ub) + ldf(B2h, 64 * qq + ub);
    }
  }

  for (int i = tid; i < 2 * PANEL + 32; i += 1024) SH[i] = (_Float16)0.0f;
  block_sync();
  if (tid < 16) {  // stage x[0] into parity-0 panel
    *(halfx8*)&SH[(tid >> 1) * SROW + XO + (tid & 1) * 8] =
        ld8(xg, ((long)0 * BB + rowbase + (tid >> 1)) * DD + (tid & 1) * 8);
  }

  // Cell ownership: (unit 4W+g, row c&7). Lanes c<8 own the L0 (cA) and L1 (cB)
  // cells; lanes c>=8 (m8) own the L2 cell (cA) — their acc regs duplicate the
  // c-8 lane's gate values, so no lane computes a redundant nonlinearity seq.
  const bool m8 = (c >= 8);
  const int r_el = c & 7;
  const int u_el = 4 * W + g;
  const int rd_off = r_el * SROW + 8 * g;
  const int wrA = r_el * SROW + u_el + (m8 ? H2O : H0O);
  const int wrB = r_el * SROW + u_el + H1O;
  const long olane = ((long)rowbase + r_el) * HH + u_el;
  float cA = 0.f, cB = 0.f;

#pragma unroll 1
  for (int s2 = 0; s2 < (TT + 2) / 2; ++s2) {
    const int s = 2 * s2;
    BODY(s, 0, PANEL)
    BODY(s + 1, PANEL, 0)
  }
}

extern "C" void kernel_launch(void* const* d_in, const int* in_sizes, int n_in,
                              void* d_out, int out_size, void* d_ws, size_t ws_size,
                              hipStream_t stream) {
  (void)in_sizes; (void)n_in; (void)out_size;
  int* flag = (ws_size >= sizeof(int)) ? (int*)d_ws : nullptr;
  if (flag) {
    detect_k<<<dim3(1), dim3(64), 0, stream>>>((const unsigned short*)d_in[0], flag);
  }
  lstm3_k<<<dim3(BB / 8), dim3(1024), 0, stream>>>(
      d_in[0],
      d_in[1], d_in[2], d_in[3], d_in[4],
      d_in[5], d_in[6], d_in[7], d_in[8],
      d_in[9], d_in[10], d_in[11], d_in[12],
      d_out, flag);
}